// Round 2
// baseline (902.851 us; speedup 1.0000x reference)
//
#include <hip/hip_runtime.h>
#include <math.h>

#define TT 8192
#define HH 768
#define II 3072
#define EE 8

typedef short bf16x8 __attribute__((ext_vector_type(8)));
typedef float f32x4 __attribute__((ext_vector_type(4)));

__device__ __forceinline__ ushort f2b(float f) {
    union { float f; unsigned int i; } x; x.f = f;
    unsigned int r = x.i + 0x7fffu + ((x.i >> 16) & 1u);
    return (ushort)(r >> 16);
}

// ---------------- permutation: bucket tokens by expert ----------------
__global__ __launch_bounds__(1024) void build_perm(const int* __restrict__ eids,
                                                   int* __restrict__ tok_sorted,
                                                   int* __restrict__ off) {
    __shared__ int cnt[EE], cur[EE], offs[EE + 1];
    int tid = threadIdx.x;
    if (tid < EE) cnt[tid] = 0;
    __syncthreads();
    for (int t = tid; t < TT; t += 1024) atomicAdd(&cnt[eids[t]], 1);
    __syncthreads();
    if (tid == 0) {
        int s = 0;
        for (int e = 0; e < EE; e++) { offs[e] = s; s += cnt[e]; }
        offs[EE] = s;
    }
    __syncthreads();
    if (tid < EE) cur[tid] = offs[tid];
    if (tid < EE + 1) off[tid] = offs[tid];
    __syncthreads();
    for (int t = tid; t < TT; t += 1024) {
        int p = atomicAdd(&cur[eids[t]], 1);
        tok_sorted[p] = t;
    }
}

// ---------------- GEMM1: inter_sorted = gelu(X[gather] @ W1[e] + b1[e]) ----------------
// grid: (EE*128, II/64), block 256. Tile BM=64,BN=64,BK=32. f32 in, bf16 LDS, bf16 out.
__global__ __launch_bounds__(256) void gemm1(const float* __restrict__ X,
                                             const float* __restrict__ W1,
                                             const float* __restrict__ B1,
                                             const int* __restrict__ tok_sorted,
                                             const int* __restrict__ off,
                                             ushort* __restrict__ inter) {
    int slot = blockIdx.x;
    int e = slot >> 7;          // 128 tile-slots per expert
    int tile = slot & 127;
    int start = off[e] + (tile << 6);
    int end = off[e + 1];
    if (start >= end) return;
    int rows = end - start; if (rows > 64) rows = 64;
    int n0 = blockIdx.y << 6;

    const float* W1e = W1 + (size_t)e * HH * II;

    __shared__ ushort As[64 * 32];   // [row][k]
    __shared__ ushort Bt[64 * 32];   // [n][k]

    int tid = threadIdx.x;
    int w = tid >> 6, lane = tid & 63, m = lane & 15, quad = lane >> 4;

    // A staging: rr = tid>>2 (row), c8 = tid&3 (8-float chunk of k)
    int rrA = tid >> 2, c8A = tid & 3;
    int tokA = tok_sorted[start + (rrA < rows ? rrA : 0)];
    const float* gA = X + (size_t)tokA * HH + c8A * 8;
    // B staging: kB = tid>>3 (k row), n8 = tid&7 (8-float chunk of n)
    int kB = tid >> 3, n8 = tid & 7;
    const float* gB = W1e + (size_t)kB * II + n0 + n8 * 8;

    f32x4 acc[4] = {};

    for (int k0 = 0; k0 < HH; k0 += 32) {
        float4 a0 = *(const float4*)(gA + k0);
        float4 a1 = *(const float4*)(gA + k0 + 4);
        float4 b0 = *(const float4*)(gB + (size_t)k0 * II);
        float4 b1 = *(const float4*)(gB + (size_t)k0 * II + 4);
        __syncthreads();
        union { ushort u[8]; uint4 v; } ta;
        ta.u[0] = f2b(a0.x); ta.u[1] = f2b(a0.y); ta.u[2] = f2b(a0.z); ta.u[3] = f2b(a0.w);
        ta.u[4] = f2b(a1.x); ta.u[5] = f2b(a1.y); ta.u[6] = f2b(a1.z); ta.u[7] = f2b(a1.w);
        *(uint4*)&As[rrA * 32 + c8A * 8] = ta.v;
        float bb[8] = {b0.x, b0.y, b0.z, b0.w, b1.x, b1.y, b1.z, b1.w};
#pragma unroll
        for (int j = 0; j < 8; j++) Bt[(n8 * 8 + j) * 32 + kB] = f2b(bb[j]);
        __syncthreads();
        bf16x8 a = *(const bf16x8*)&As[(w * 16 + m) * 32 + quad * 8];
#pragma unroll
        for (int nb = 0; nb < 4; nb++) {
            bf16x8 b = *(const bf16x8*)&Bt[(nb * 16 + m) * 32 + quad * 8];
            acc[nb] = __builtin_amdgcn_mfma_f32_16x16x32_bf16(a, b, acc[nb], 0, 0, 0);
        }
    }

    const float* b1e = B1 + (size_t)e * II;
#pragma unroll
    for (int nb = 0; nb < 4; nb++) {
        int col = n0 + nb * 16 + m;
        float bias = b1e[col];
#pragma unroll
        for (int r = 0; r < 4; r++) {
            int row = w * 16 + quad * 4 + r;
            if (row < rows) {
                float v = acc[nb][r] + bias;
                v = 0.5f * v * (1.0f + erff(v * 0.70710678118654752f));
                inter[(size_t)(start + row) * II + col] = f2b(v);
            }
        }
    }
}

// ---------------- GEMM2: sel_sorted = inter_sorted @ W2[e] + b2[e] (f32 out) ----------------
// grid: (EE*128, HH/64), block 256. A is bf16 (inter), B is f32 (W2).
__global__ __launch_bounds__(256) void gemm2(const ushort* __restrict__ inter,
                                             const float* __restrict__ W2,
                                             const float* __restrict__ B2,
                                             const int* __restrict__ off,
                                             float* __restrict__ sel) {
    int slot = blockIdx.x;
    int e = slot >> 7;
    int tile = slot & 127;
    int start = off[e] + (tile << 6);
    int end = off[e + 1];
    if (start >= end) return;
    int rows = end - start; if (rows > 64) rows = 64;
    int n0 = blockIdx.y << 6;

    const float* W2e = W2 + (size_t)e * II * HH;

    __shared__ ushort As[64 * 32];
    __shared__ ushort Bt[64 * 32];

    int tid = threadIdx.x;
    int w = tid >> 6, lane = tid & 63, m = lane & 15, quad = lane >> 4;

    int rrA = tid >> 2, c8A = tid & 3;
    int rA = start + rrA; if (rA > TT - 1) rA = TT - 1;
    const ushort* gA = inter + (size_t)rA * II + c8A * 8;
    int kB = tid >> 3, n8 = tid & 7;
    const float* gB = W2e + (size_t)kB * HH + n0 + n8 * 8;

    f32x4 acc[4] = {};

    for (int k0 = 0; k0 < II; k0 += 32) {
        uint4 av = *(const uint4*)(gA + k0);             // 8 bf16
        float4 b0 = *(const float4*)(gB + (size_t)k0 * HH);
        float4 b1 = *(const float4*)(gB + (size_t)k0 * HH + 4);
        __syncthreads();
        *(uint4*)&As[rrA * 32 + c8A * 8] = av;
        float bb[8] = {b0.x, b0.y, b0.z, b0.w, b1.x, b1.y, b1.z, b1.w};
#pragma unroll
        for (int j = 0; j < 8; j++) Bt[(n8 * 8 + j) * 32 + kB] = f2b(bb[j]);
        __syncthreads();
        bf16x8 a = *(const bf16x8*)&As[(w * 16 + m) * 32 + quad * 8];
#pragma unroll
        for (int nb = 0; nb < 4; nb++) {
            bf16x8 b = *(const bf16x8*)&Bt[(nb * 16 + m) * 32 + quad * 8];
            acc[nb] = __builtin_amdgcn_mfma_f32_16x16x32_bf16(a, b, acc[nb], 0, 0, 0);
        }
    }

    const float* b2e = B2 + (size_t)e * HH;
#pragma unroll
    for (int nb = 0; nb < 4; nb++) {
        int col = n0 + nb * 16 + m;
        float bias = b2e[col];
#pragma unroll
        for (int r = 0; r < 4; r++) {
            int row = w * 16 + quad * 4 + r;
            if (row < rows) {
                sel[(size_t)(start + row) * HH + col] = acc[nb][r] + bias;
            }
        }
    }
}

// ---------------- residual + LayerNorm + scatter to token order ----------------
// grid: TT blocks of 256. All f32.
__global__ __launch_bounds__(256) void ln_kernel(const float* __restrict__ sel,
                                                 const float* __restrict__ X,
                                                 const float* __restrict__ gamma,
                                                 const float* __restrict__ beta,
                                                 const int* __restrict__ tok_sorted,
                                                 float* __restrict__ out) {
    int r = blockIdx.x;
    int tok = tok_sorted[r];
    int tid = threadIdx.x;

    float v[3];
    float s = 0.f, s2 = 0.f;
#pragma unroll
    for (int j = 0; j < 3; j++) {
        int h = tid + j * 256;
        float t = sel[(size_t)r * HH + h] + X[(size_t)tok * HH + h];
        v[j] = t; s += t; s2 += t * t;
    }
#pragma unroll
    for (int o = 32; o > 0; o >>= 1) {
        s += __shfl_down(s, o);
        s2 += __shfl_down(s2, o);
    }
    __shared__ float ws1[4], ws2[4];
    int lane = tid & 63, w = tid >> 6;
    if (lane == 0) { ws1[w] = s; ws2[w] = s2; }
    __syncthreads();
    __shared__ float mu_s, rs_s;
    if (tid == 0) {
        float a = 0.f, b = 0.f;
        for (int i = 0; i < 4; i++) { a += ws1[i]; b += ws2[i]; }
        float mu = a / (float)HH;
        float var = b / (float)HH - mu * mu;
        mu_s = mu;
        rs_s = rsqrtf(var + 1e-12f);
    }
    __syncthreads();
    float mu = mu_s, rs = rs_s;
#pragma unroll
    for (int j = 0; j < 3; j++) {
        int h = tid + j * 256;
        float o = (v[j] - mu) * rs * gamma[h] + beta[h];
        out[(size_t)tok * HH + h] = o;
    }
}

extern "C" void kernel_launch(void* const* d_in, const int* in_sizes, int n_in,
                              void* d_out, int out_size, void* d_ws, size_t ws_size,
                              hipStream_t stream) {
    const float* X  = (const float*)d_in[0];   // [1,T,H] f32
    const float* W1 = (const float*)d_in[1];   // [E,H,I] f32
    const float* B1 = (const float*)d_in[2];   // [E,1,I] f32
    const float* W2 = (const float*)d_in[3];   // [E,I,H] f32
    const float* B2 = (const float*)d_in[4];   // [E,1,H] f32
    const float* G  = (const float*)d_in[5];   // [H] f32
    const float* Bt = (const float*)d_in[6];   // [H] f32
    const int* eids  = (const int*)d_in[7];    // [T] int32
    float* out = (float*)d_out;

    char* ws = (char*)d_ws;
    int* off = (int*)ws;                                   // 16 ints
    int* tok_sorted = (int*)(ws + 64);                     // T ints
    ushort* inter = (ushort*)(ws + 64 + 4 * TT);           // T*I bf16 (50 MB)
    float* sel = (float*)(ws + 64 + 4 * TT + (size_t)2 * TT * II);  // T*H f32 (25 MB)

    build_perm<<<1, 1024, 0, stream>>>(eids, tok_sorted, off);
    gemm1<<<dim3(EE * 128, II / 64), 256, 0, stream>>>(X, W1, B1, tok_sorted, off, inter);
    gemm2<<<dim3(EE * 128, HH / 64), 256, 0, stream>>>(inter, W2, B2, off, sel);
    ln_kernel<<<TT, 256, 0, stream>>>(sel, X, G, Bt, tok_sorted, out);
}

// Round 3
// 413.339 us; speedup vs baseline: 2.1843x; 2.1843x over previous
//
#include <hip/hip_runtime.h>
#include <math.h>

#define TT 8192
#define HH 768
#define II 3072
#define EE 8
#define MAXT 72

typedef short bf16x8 __attribute__((ext_vector_type(8)));
typedef float f32x4 __attribute__((ext_vector_type(4)));

__device__ __forceinline__ ushort f2b(float f) {
    union { float f; unsigned int i; } x; x.f = f;
    unsigned int r = x.i + 0x7fffu + ((x.i >> 16) & 1u);
    return (ushort)(r >> 16);
}

__device__ __forceinline__ void glds16(const ushort* g, ushort* l) {
    __builtin_amdgcn_global_load_lds(
        (const __attribute__((address_space(1))) void*)g,
        (__attribute__((address_space(3))) void*)l, 16, 0, 0);
}

// ---------------- permutation + tile map ----------------
__global__ __launch_bounds__(1024) void build_perm(const int* __restrict__ eids,
                                                   int* __restrict__ tok_sorted,
                                                   int* __restrict__ off,
                                                   int* __restrict__ meta,
                                                   int write_tiles) {
    __shared__ int cnt[EE], cur[EE], offs[EE + 1];
    int tid = threadIdx.x;
    if (tid < EE) cnt[tid] = 0;
    __syncthreads();
    for (int t = tid; t < TT; t += 1024) atomicAdd(&cnt[eids[t]], 1);
    __syncthreads();
    if (tid == 0) {
        int s = 0;
        for (int e = 0; e < EE; e++) { offs[e] = s; s += cnt[e]; }
        offs[EE] = s;
        if (write_tiles) {
            int nt = 0;
            for (int e = 0; e < EE; e++) {
                int c = offs[e + 1] - offs[e];
                for (int m0 = 0; m0 < c; m0 += 128) {
                    meta[16 + nt] = e;
                    meta[96 + nt] = offs[e] + m0;
                    meta[176 + nt] = (c - m0 < 128) ? (c - m0) : 128;
                    nt++;
                }
            }
            meta[0] = nt;
        }
    }
    __syncthreads();
    if (tid < EE) cur[tid] = offs[tid];
    if (tid < EE + 1) off[tid] = offs[tid];
    __syncthreads();
    for (int t = tid; t < TT; t += 1024) {
        int p = atomicAdd(&cur[eids[t]], 1);
        tok_sorted[p] = t;
    }
}

// ---------------- gather + f32->bf16 convert of X into sorted order ----------------
__global__ __launch_bounds__(192) void cvtX(const float* __restrict__ X,
                                            const int* __restrict__ tok_sorted,
                                            ushort* __restrict__ Xs) {
    int r = blockIdx.x;
    int t = tok_sorted[r];
    int h = threadIdx.x * 4;
    float4 v = *(const float4*)(X + (size_t)t * HH + h);
    ushort4 o;
    o.x = f2b(v.x); o.y = f2b(v.y); o.z = f2b(v.z); o.w = f2b(v.w);
    *(ushort4*)(Xs + (size_t)r * HH + h) = o;
}

// ---------------- transpose + convert: src f32 [R][C] -> dst bf16 [C][R], per expert z ----------------
__global__ __launch_bounds__(256) void tcvt(const float* __restrict__ src0,
                                            ushort* __restrict__ dst0, int R, int C) {
    int e = blockIdx.z;
    const float* src = src0 + (size_t)e * R * C;
    ushort* dst = dst0 + (size_t)e * R * C;
    int c0 = blockIdx.x * 64, r0 = blockIdx.y * 64;
    __shared__ float T[64][65];
    int lr = threadIdx.x >> 2, lc4 = threadIdx.x & 3;
#pragma unroll
    for (int i = 0; i < 4; i++) {
        int c = lc4 * 16 + i * 4;
        float4 v = *(const float4*)(src + (size_t)(r0 + lr) * C + c0 + c);
        T[lr][c] = v.x; T[lr][c + 1] = v.y; T[lr][c + 2] = v.z; T[lr][c + 3] = v.w;
    }
    __syncthreads();
    int oc = threadIdx.x >> 2, og = threadIdx.x & 3;
    union { ushort u[8]; uint4 v; } p0, p1;
#pragma unroll
    for (int j = 0; j < 8; j++) {
        p0.u[j] = f2b(T[og * 16 + j][oc]);
        p1.u[j] = f2b(T[og * 16 + 8 + j][oc]);
    }
    uint4* dp = (uint4*)(dst + (size_t)(c0 + oc) * R + r0 + og * 16);
    dp[0] = p0.v; dp[1] = p1.v;
}

// ---------------- m97-style grouped GEMM: C = act(A @ B^T + bias) ----------------
// A: bf16 [rows_sorted][KT] (padded +128 rows). B: bf16 [E][NT][KT]. bias f32 [E][NT].
// grid: (MAXT, NT/128), block 256 (4 waves, each 64x64 via 4x4 of 16x16x32).
template<int KT, int NT, bool GELU, bool OUTF32>
__global__ __launch_bounds__(256) void gemm_k(const ushort* __restrict__ A,
                                              const ushort* __restrict__ B,
                                              const float* __restrict__ bias,
                                              const int* __restrict__ meta,
                                              void* __restrict__ outp) {
    int bx = blockIdx.x;
    if (bx >= meta[0]) return;
    int e = meta[16 + bx];
    int start = meta[96 + bx];
    int rows = meta[176 + bx];
    int n0 = blockIdx.y * 128;

    const ushort* Be = B + (size_t)e * NT * KT;
    const float* be = bias + (size_t)e * NT;

    __shared__ ushort As[128 * 32];
    __shared__ ushort Bs[128 * 32];

    int tid = threadIdx.x;
    int lane = tid & 63, m = lane & 15, quad = lane >> 4;
    int wv = tid >> 6, wm = wv & 1, wn = wv >> 1;

    // staging maps: t = tid + j*256 -> LDS byte t*16; row = t>>2, kchunk = t&3
    int r0a = tid >> 2, kc = tid & 3;
    const ushort* ga0 = A + (size_t)(start + r0a) * KT + kc * 8;
    const ushort* ga1 = ga0 + (size_t)64 * KT;
    const ushort* gb0 = Be + (size_t)(n0 + r0a) * KT + kc * 8;
    const ushort* gb1 = gb0 + (size_t)64 * KT;
    char* lA = (char*)As + (wv << 10);
    char* lB = (char*)Bs + (wv << 10);

    f32x4 acc[4][4] = {};

    const ushort* pa = As + ((size_t)(wm * 64 + m)) * 32 + quad * 8;
    const ushort* pb = Bs + ((size_t)(wn * 64 + m)) * 32 + quad * 8;

    for (int k0 = 0; k0 < KT; k0 += 32) {
        __syncthreads();
        glds16(ga0, (ushort*)lA);
        glds16(ga1, (ushort*)(lA + 4096));
        glds16(gb0, (ushort*)lB);
        glds16(gb1, (ushort*)(lB + 4096));
        ga0 += 32; ga1 += 32; gb0 += 32; gb1 += 32;
        __syncthreads();
        bf16x8 a[4], b[4];
#pragma unroll
        for (int i = 0; i < 4; i++) a[i] = *(const bf16x8*)(pa + (size_t)i * 16 * 32);
#pragma unroll
        for (int j = 0; j < 4; j++) b[j] = *(const bf16x8*)(pb + (size_t)j * 16 * 32);
#pragma unroll
        for (int i = 0; i < 4; i++)
#pragma unroll
            for (int j = 0; j < 4; j++)
                acc[i][j] = __builtin_amdgcn_mfma_f32_16x16x32_bf16(a[i], b[j], acc[i][j], 0, 0, 0);
    }

    float bv[4];
#pragma unroll
    for (int j = 0; j < 4; j++) bv[j] = be[n0 + wn * 64 + j * 16 + m];

#pragma unroll
    for (int i = 0; i < 4; i++) {
#pragma unroll
        for (int r = 0; r < 4; r++) {
            int row = wm * 64 + i * 16 + quad * 4 + r;
            if (row < rows) {
#pragma unroll
                for (int j = 0; j < 4; j++) {
                    int col = n0 + wn * 64 + j * 16 + m;
                    float v = acc[i][j][r] + bv[j];
                    if (GELU) v = 0.5f * v * (1.0f + erff(v * 0.70710678118654752f));
                    if (OUTF32) ((float*)outp)[(size_t)(start + row) * NT + col] = v;
                    else ((ushort*)outp)[(size_t)(start + row) * NT + col] = f2b(v);
                }
            }
        }
    }
}

// ---------------- residual + LayerNorm + scatter ----------------
__global__ __launch_bounds__(256) void ln_kernel(const float* __restrict__ sel,
                                                 const float* __restrict__ X,
                                                 const float* __restrict__ gamma,
                                                 const float* __restrict__ beta,
                                                 const int* __restrict__ tok_sorted,
                                                 float* __restrict__ out) {
    int r = blockIdx.x;
    int tok = tok_sorted[r];
    int tid = threadIdx.x;

    float v[3];
    float s = 0.f, s2 = 0.f;
#pragma unroll
    for (int j = 0; j < 3; j++) {
        int h = tid + j * 256;
        float t = sel[(size_t)r * HH + h] + X[(size_t)tok * HH + h];
        v[j] = t; s += t; s2 += t * t;
    }
#pragma unroll
    for (int o = 32; o > 0; o >>= 1) {
        s += __shfl_down(s, o);
        s2 += __shfl_down(s2, o);
    }
    __shared__ float ws1[4], ws2[4];
    int lane = tid & 63, w = tid >> 6;
    if (lane == 0) { ws1[w] = s; ws2[w] = s2; }
    __syncthreads();
    __shared__ float mu_s, rs_s;
    if (tid == 0) {
        float a = 0.f, b = 0.f;
        for (int i = 0; i < 4; i++) { a += ws1[i]; b += ws2[i]; }
        float mu = a / (float)HH;
        float var = b / (float)HH - mu * mu;
        mu_s = mu;
        rs_s = rsqrtf(var + 1e-12f);
    }
    __syncthreads();
    float mu = mu_s, rs = rs_s;
#pragma unroll
    for (int j = 0; j < 3; j++) {
        int h = tid + j * 256;
        float o = (v[j] - mu) * rs * gamma[h] + beta[h];
        out[(size_t)tok * HH + h] = o;
    }
}

// ================= fallback (R1) small-tile kernels, used if ws too small =================
__global__ __launch_bounds__(256) void gemm1_s(const float* __restrict__ X,
                                               const float* __restrict__ W1,
                                               const float* __restrict__ B1,
                                               const int* __restrict__ tok_sorted,
                                               const int* __restrict__ off,
                                               ushort* __restrict__ inter) {
    int slot = blockIdx.x;
    int e = slot >> 7, tile = slot & 127;
    int start = off[e] + (tile << 6);
    int end = off[e + 1];
    if (start >= end) return;
    int rows = end - start; if (rows > 64) rows = 64;
    int n0 = blockIdx.y << 6;
    const float* W1e = W1 + (size_t)e * HH * II;
    __shared__ ushort As[64 * 32];
    __shared__ ushort Bt[64 * 32];
    int tid = threadIdx.x;
    int w = tid >> 6, lane = tid & 63, m = lane & 15, quad = lane >> 4;
    int rrA = tid >> 2, c8A = tid & 3;
    int tokA = tok_sorted[start + (rrA < rows ? rrA : 0)];
    const float* gA = X + (size_t)tokA * HH + c8A * 8;
    int kB = tid >> 3, n8 = tid & 7;
    const float* gB = W1e + (size_t)kB * II + n0 + n8 * 8;
    f32x4 acc[4] = {};
    for (int k0 = 0; k0 < HH; k0 += 32) {
        float4 a0 = *(const float4*)(gA + k0);
        float4 a1 = *(const float4*)(gA + k0 + 4);
        float4 b0 = *(const float4*)(gB + (size_t)k0 * II);
        float4 b1 = *(const float4*)(gB + (size_t)k0 * II + 4);
        __syncthreads();
        union { ushort u[8]; uint4 v; } ta;
        ta.u[0] = f2b(a0.x); ta.u[1] = f2b(a0.y); ta.u[2] = f2b(a0.z); ta.u[3] = f2b(a0.w);
        ta.u[4] = f2b(a1.x); ta.u[5] = f2b(a1.y); ta.u[6] = f2b(a1.z); ta.u[7] = f2b(a1.w);
        *(uint4*)&As[rrA * 32 + c8A * 8] = ta.v;
        float bb[8] = {b0.x, b0.y, b0.z, b0.w, b1.x, b1.y, b1.z, b1.w};
#pragma unroll
        for (int j = 0; j < 8; j++) Bt[(n8 * 8 + j) * 32 + kB] = f2b(bb[j]);
        __syncthreads();
        bf16x8 a = *(const bf16x8*)&As[(w * 16 + m) * 32 + quad * 8];
#pragma unroll
        for (int nb = 0; nb < 4; nb++) {
            bf16x8 b = *(const bf16x8*)&Bt[(nb * 16 + m) * 32 + quad * 8];
            acc[nb] = __builtin_amdgcn_mfma_f32_16x16x32_bf16(a, b, acc[nb], 0, 0, 0);
        }
    }
    const float* b1e = B1 + (size_t)e * II;
#pragma unroll
    for (int nb = 0; nb < 4; nb++) {
        int col = n0 + nb * 16 + m;
        float bias = b1e[col];
#pragma unroll
        for (int r = 0; r < 4; r++) {
            int row = w * 16 + quad * 4 + r;
            if (row < rows) {
                float v = acc[nb][r] + bias;
                v = 0.5f * v * (1.0f + erff(v * 0.70710678118654752f));
                inter[(size_t)(start + row) * II + col] = f2b(v);
            }
        }
    }
}

__global__ __launch_bounds__(256) void gemm2_s(const ushort* __restrict__ inter,
                                               const float* __restrict__ W2,
                                               const float* __restrict__ B2,
                                               const int* __restrict__ off,
                                               float* __restrict__ sel) {
    int slot = blockIdx.x;
    int e = slot >> 7, tile = slot & 127;
    int start = off[e] + (tile << 6);
    int end = off[e + 1];
    if (start >= end) return;
    int rows = end - start; if (rows > 64) rows = 64;
    int n0 = blockIdx.y << 6;
    const float* W2e = W2 + (size_t)e * II * HH;
    __shared__ ushort As[64 * 32];
    __shared__ ushort Bt[64 * 32];
    int tid = threadIdx.x;
    int w = tid >> 6, lane = tid & 63, m = lane & 15, quad = lane >> 4;
    int rrA = tid >> 2, c8A = tid & 3;
    int rA = start + rrA; if (rA > TT - 1) rA = TT - 1;
    const ushort* gA = inter + (size_t)rA * II + c8A * 8;
    int kB = tid >> 3, n8 = tid & 7;
    const float* gB = W2e + (size_t)kB * HH + n0 + n8 * 8;
    f32x4 acc[4] = {};
    for (int k0 = 0; k0 < II; k0 += 32) {
        uint4 av = *(const uint4*)(gA + k0);
        float4 b0 = *(const float4*)(gB + (size_t)k0 * HH);
        float4 b1 = *(const float4*)(gB + (size_t)k0 * HH + 4);
        __syncthreads();
        *(uint4*)&As[rrA * 32 + c8A * 8] = av;
        float bb[8] = {b0.x, b0.y, b0.z, b0.w, b1.x, b1.y, b1.z, b1.w};
#pragma unroll
        for (int j = 0; j < 8; j++) Bt[(n8 * 8 + j) * 32 + kB] = f2b(bb[j]);
        __syncthreads();
        bf16x8 a = *(const bf16x8*)&As[(w * 16 + m) * 32 + quad * 8];
#pragma unroll
        for (int nb = 0; nb < 4; nb++) {
            bf16x8 b = *(const bf16x8*)&Bt[(nb * 16 + m) * 32 + quad * 8];
            acc[nb] = __builtin_amdgcn_mfma_f32_16x16x32_bf16(a, b, acc[nb], 0, 0, 0);
        }
    }
    const float* b2e = B2 + (size_t)e * HH;
#pragma unroll
    for (int nb = 0; nb < 4; nb++) {
        int col = n0 + nb * 16 + m;
        float bias = b2e[col];
#pragma unroll
        for (int r = 0; r < 4; r++) {
            int row = w * 16 + quad * 4 + r;
            if (row < rows) sel[(size_t)(start + row) * HH + col] = acc[nb][r] + bias;
        }
    }
}

extern "C" void kernel_launch(void* const* d_in, const int* in_sizes, int n_in,
                              void* d_out, int out_size, void* d_ws, size_t ws_size,
                              hipStream_t stream) {
    const float* X  = (const float*)d_in[0];
    const float* W1 = (const float*)d_in[1];
    const float* B1 = (const float*)d_in[2];
    const float* W2 = (const float*)d_in[3];
    const float* B2 = (const float*)d_in[4];
    const float* G  = (const float*)d_in[5];
    const float* Bt = (const float*)d_in[6];
    const int* eids = (const int*)d_in[7];
    float* out = (float*)d_out;
    char* ws = (char*)d_ws;

    const size_t XS_OFF    = 34816;
    const size_t XS_SZ     = (size_t)2 * (TT + 128) * HH;       // 12,779,520
    const size_t W1T_OFF   = XS_OFF + XS_SZ;                     // 12,814,336
    const size_t W1T_SZ    = (size_t)2 * EE * HH * II;           // 37,748,736
    const size_t W2T_OFF   = W1T_OFF + W1T_SZ;                   // 50,563,072
    const size_t INTER_OFF = W2T_OFF + W1T_SZ;                   // 88,311,808
    const size_t INTER_SZ  = (size_t)2 * (TT + 128) * II;        // 51,118,080
    const size_t SEL_OFF   = INTER_OFF + INTER_SZ;               // 139,429,888
    const size_t SEL_SZ    = (size_t)4 * TT * HH;                // 25,165,824
    const size_t NEED      = SEL_OFF + SEL_SZ;                   // 164,595,712

    if (ws_size >= NEED) {
        int* off = (int*)ws;                    // 64 B
        int* meta = (int*)(ws + 64);            // ~1 KB
        int* tok = (int*)(ws + 2048);           // 32 KB
        ushort* Xs = (ushort*)(ws + XS_OFF);
        ushort* W1t = (ushort*)(ws + W1T_OFF);
        ushort* W2t = (ushort*)(ws + W2T_OFF);
        ushort* inter = (ushort*)(ws + INTER_OFF);
        float* sel = (float*)(ws + SEL_OFF);

        build_perm<<<1, 1024, 0, stream>>>(eids, tok, off, meta, 1);
        cvtX<<<TT, 192, 0, stream>>>(X, tok, Xs);
        tcvt<<<dim3(II / 64, HH / 64, EE), 256, 0, stream>>>(W1, W1t, HH, II);
        tcvt<<<dim3(HH / 64, II / 64, EE), 256, 0, stream>>>(W2, W2t, II, HH);
        gemm_k<HH, II, true, false><<<dim3(MAXT, II / 128), 256, 0, stream>>>(Xs, W1t, B1, meta, inter);
        gemm_k<II, HH, false, true><<<dim3(MAXT, HH / 128), 256, 0, stream>>>(inter, W2t, B2, meta, sel);
        ln_kernel<<<TT, 256, 0, stream>>>(sel, X, G, Bt, tok, out);
    } else {
        int* off = (int*)ws;
        int* tok = (int*)(ws + 64);
        ushort* inter = (ushort*)(ws + 64 + 4 * TT);
        float* sel = (float*)(ws + 64 + 4 * TT + (size_t)2 * TT * II);
        build_perm<<<1, 1024, 0, stream>>>(eids, tok, off, off, 0);
        gemm1_s<<<dim3(EE * 128, II / 64), 256, 0, stream>>>(X, W1, B1, tok, off, inter);
        gemm2_s<<<dim3(EE * 128, HH / 64), 256, 0, stream>>>(inter, W2, B2, off, sel);
        ln_kernel<<<TT, 256, 0, stream>>>(sel, X, G, Bt, tok, out);
    }
}

// Round 4
// 383.503 us; speedup vs baseline: 2.3542x; 1.0778x over previous
//
#include <hip/hip_runtime.h>
#include <math.h>

#define TT 8192
#define HH 768
#define II 3072
#define EE 8
#define MAXT 72

typedef short bf16x8 __attribute__((ext_vector_type(8)));
typedef float f32x4 __attribute__((ext_vector_type(4)));

__device__ __forceinline__ ushort f2b(float f) {
    union { float f; unsigned int i; } x; x.f = f;
    unsigned int r = x.i + 0x7fffu + ((x.i >> 16) & 1u);
    return (ushort)(r >> 16);
}
__device__ __forceinline__ float b2f(ushort u) {
    union { unsigned int i; float f; } x; x.i = ((unsigned int)u) << 16; return x.f;
}

__device__ __forceinline__ void glds16(const ushort* g, ushort* l) {
    __builtin_amdgcn_global_load_lds(
        (const __attribute__((address_space(1))) void*)g,
        (__attribute__((address_space(3))) void*)l, 16, 0, 0);
}

// A&S 7.1.26 erf (max abs err 1.5e-7) -> exact-GELU
__device__ __forceinline__ float fast_gelu(float v) {
    float x = v * 0.70710678118654752f;
    float ax = fabsf(x);
    float t = __builtin_amdgcn_rcpf(__builtin_fmaf(0.3275911f, ax, 1.0f));
    float p = __builtin_fmaf(t, 1.061405429f, -1.453152027f);
    p = __builtin_fmaf(t, p, 1.421413741f);
    p = __builtin_fmaf(t, p, -0.284496736f);
    p = __builtin_fmaf(t, p, 0.254829592f);
    p = p * t;
    float e = __expf(-ax * ax);
    float erf_abs = 1.0f - p * e;
    float er = (x < 0.0f) ? -erf_abs : erf_abs;
    return 0.5f * v * (1.0f + er);
}

// ---------------- permutation + tile map ----------------
__global__ __launch_bounds__(1024) void build_perm(const int* __restrict__ eids,
                                                   int* __restrict__ tok_sorted,
                                                   int* __restrict__ off,
                                                   int* __restrict__ meta,
                                                   int write_tiles) {
    __shared__ int cnt[EE], cur[EE], offs[EE + 1];
    int tid = threadIdx.x;
    if (tid < EE) cnt[tid] = 0;
    __syncthreads();
    for (int t = tid; t < TT; t += 1024) atomicAdd(&cnt[eids[t]], 1);
    __syncthreads();
    if (tid == 0) {
        int s = 0;
        for (int e = 0; e < EE; e++) { offs[e] = s; s += cnt[e]; }
        offs[EE] = s;
        if (write_tiles) {
            int nt = 0;
            for (int e = 0; e < EE; e++) {
                int c = offs[e + 1] - offs[e];
                for (int m0 = 0; m0 < c; m0 += 128) {
                    meta[16 + nt] = e;
                    meta[96 + nt] = offs[e] + m0;
                    meta[176 + nt] = (c - m0 < 128) ? (c - m0) : 128;
                    nt++;
                }
            }
            meta[0] = nt;
        }
    }
    __syncthreads();
    if (tid < EE) cur[tid] = offs[tid];
    if (tid < EE + 1) off[tid] = offs[tid];
    __syncthreads();
    for (int t = tid; t < TT; t += 1024) {
        int p = atomicAdd(&cur[eids[t]], 1);
        tok_sorted[p] = t;
    }
}

// ---------------- gather + f32->bf16 convert of X into sorted order ----------------
__global__ __launch_bounds__(192) void cvtX(const float* __restrict__ X,
                                            const int* __restrict__ tok_sorted,
                                            ushort* __restrict__ Xs) {
    int r = blockIdx.x;
    int t = tok_sorted[r];
    int h = threadIdx.x * 4;
    float4 v = *(const float4*)(X + (size_t)t * HH + h);
    ushort4 o;
    o.x = f2b(v.x); o.y = f2b(v.y); o.z = f2b(v.z); o.w = f2b(v.w);
    *(ushort4*)(Xs + (size_t)r * HH + h) = o;
}

// ---------------- transpose + convert both weights: f32 [R][C] -> bf16 [C][R] ----------------
// grid: (576, EE, 2)  z=0: W1 (R=HH,C=II); z=1: W2 (R=II,C=HH)
__global__ __launch_bounds__(256) void tcvt2(const float* __restrict__ W1,
                                             const float* __restrict__ W2,
                                             ushort* __restrict__ W1t,
                                             ushort* __restrict__ W2t) {
    int which = blockIdx.z;
    int R = which ? II : HH;
    int C = which ? HH : II;
    const float* src = (which ? W2 : W1) + (size_t)blockIdx.y * R * C;
    ushort* dst = (which ? W2t : W1t) + (size_t)blockIdx.y * R * C;
    int ctiles = C >> 6;
    int c0 = (blockIdx.x % ctiles) * 64, r0 = (blockIdx.x / ctiles) * 64;
    __shared__ float T[64][65];
    int lr = threadIdx.x >> 2, lc4 = threadIdx.x & 3;
#pragma unroll
    for (int i = 0; i < 4; i++) {
        int c = lc4 * 16 + i * 4;
        float4 v = *(const float4*)(src + (size_t)(r0 + lr) * C + c0 + c);
        T[lr][c] = v.x; T[lr][c + 1] = v.y; T[lr][c + 2] = v.z; T[lr][c + 3] = v.w;
    }
    __syncthreads();
    int oc = threadIdx.x >> 2, og = threadIdx.x & 3;
    union { ushort u[8]; uint4 v; } p0, p1;
#pragma unroll
    for (int j = 0; j < 8; j++) {
        p0.u[j] = f2b(T[og * 16 + j][oc]);
        p1.u[j] = f2b(T[og * 16 + 8 + j][oc]);
    }
    uint4* dp = (uint4*)(dst + (size_t)(c0 + oc) * R + r0 + og * 16);
    dp[0] = p0.v; dp[1] = p1.v;
}

// ---------------- grouped GEMM: C = act(A @ B^T + bias [+ residual]) ----------------
// BK=64 (two 32-K sub-tiles per barrier pair), XOR-swizzled LDS, 128x128 tile, 3 blocks/CU.
template<int KT, int NT, bool GELU, bool OUTF32, bool RES>
__global__ __launch_bounds__(256, 3) void gemm_k(const ushort* __restrict__ A,
                                                 const ushort* __restrict__ B,
                                                 const float* __restrict__ bias,
                                                 const ushort* __restrict__ Xs,
                                                 const int* __restrict__ meta,
                                                 void* __restrict__ outp) {
    int bx = blockIdx.x;
    if (bx >= meta[0]) return;
    int e = meta[16 + bx];
    int start = meta[96 + bx];
    int rows = meta[176 + bx];
    int n0 = blockIdx.y * 128;

    const ushort* Be = B + (size_t)e * NT * KT;
    const float* be = bias + (size_t)e * NT;

    __shared__ ushort As0[4096], As1[4096], Bs0[4096], Bs1[4096];

    int tid = threadIdx.x;
    int lane = tid & 63, m = lane & 15, quad = lane >> 4;
    int wv = tid >> 6, wm = wv & 1, wn = wv >> 1;

    // staging: slot s holds (row r = s>>2, chunk c = s&3), storing src kchunk c ^ ((r>>1)&3)
    int rA = tid >> 2;
    int kcs = (tid & 3) ^ ((tid >> 3) & 3);
    const ushort* ga0 = A + (size_t)(start + rA) * KT + kcs * 8;
    const ushort* ga1 = ga0 + (size_t)64 * KT;
    const ushort* gb0 = Be + (size_t)(n0 + rA) * KT + kcs * 8;
    const ushort* gb1 = gb0 + (size_t)64 * KT;
    ushort* dA0a = As0 + wv * 512;
    ushort* dA0b = As0 + 2048 + wv * 512;
    ushort* dB0a = Bs0 + wv * 512;
    ushort* dB0b = Bs0 + 2048 + wv * 512;
    ushort* dA1a = As1 + wv * 512;
    ushort* dA1b = As1 + 2048 + wv * 512;
    ushort* dB1a = Bs1 + wv * 512;
    ushort* dB1b = Bs1 + 2048 + wv * 512;

    f32x4 acc[4][4] = {};

    // fragment read offsets (swizzled): qx = quad ^ ((m>>1)&3)
    int qx = quad ^ ((m >> 1) & 3);
    int foA = (wm * 64 + m) * 32 + qx * 8;
    int foB = (wn * 64 + m) * 32 + qx * 8;

    for (int k0 = 0; k0 < KT; k0 += 64) {
        __syncthreads();
        glds16(ga0, dA0a);
        glds16(ga1, dA0b);
        glds16(gb0, dB0a);
        glds16(gb1, dB0b);
        glds16(ga0 + 32, dA1a);
        glds16(ga1 + 32, dA1b);
        glds16(gb0 + 32, dB1a);
        glds16(gb1 + 32, dB1b);
        ga0 += 64; ga1 += 64; gb0 += 64; gb1 += 64;
        __syncthreads();
#pragma unroll
        for (int s = 0; s < 2; s++) {
            const ushort* as = s ? As1 : As0;
            const ushort* bs = s ? Bs1 : Bs0;
            bf16x8 a[4], b[4];
#pragma unroll
            for (int i = 0; i < 4; i++) a[i] = *(const bf16x8*)(as + foA + i * 16 * 32);
#pragma unroll
            for (int j = 0; j < 4; j++) b[j] = *(const bf16x8*)(bs + foB + j * 16 * 32);
#pragma unroll
            for (int i = 0; i < 4; i++)
#pragma unroll
                for (int j = 0; j < 4; j++)
                    acc[i][j] = __builtin_amdgcn_mfma_f32_16x16x32_bf16(a[i], b[j], acc[i][j], 0, 0, 0);
        }
    }

    float bv[4];
#pragma unroll
    for (int j = 0; j < 4; j++) bv[j] = be[n0 + wn * 64 + j * 16 + m];

#pragma unroll
    for (int i = 0; i < 4; i++) {
#pragma unroll
        for (int r = 0; r < 4; r++) {
            int row = wm * 64 + i * 16 + quad * 4 + r;
            if (row < rows) {
#pragma unroll
                for (int j = 0; j < 4; j++) {
                    int col = n0 + wn * 64 + j * 16 + m;
                    float v = acc[i][j][r] + bv[j];
                    if (RES) v += b2f(Xs[(size_t)(start + row) * NT + col]);
                    if (GELU) v = fast_gelu(v);
                    if (OUTF32) ((float*)outp)[(size_t)(start + row) * NT + col] = v;
                    else ((ushort*)outp)[(size_t)(start + row) * NT + col] = f2b(v);
                }
            }
        }
    }
}

// ---------------- LayerNorm (+optional residual for fallback) + scatter ----------------
__global__ __launch_bounds__(256) void ln_kernel(const float* __restrict__ sel,
                                                 const float* __restrict__ X,
                                                 const float* __restrict__ gamma,
                                                 const float* __restrict__ beta,
                                                 const int* __restrict__ tok_sorted,
                                                 float* __restrict__ out,
                                                 int add_res) {
    int r = blockIdx.x;
    int tok = tok_sorted[r];
    int tid = threadIdx.x;

    float v[3];
    float s = 0.f, s2 = 0.f;
#pragma unroll
    for (int j = 0; j < 3; j++) {
        int h = tid + j * 256;
        float t = sel[(size_t)r * HH + h];
        if (add_res) t += X[(size_t)tok * HH + h];
        v[j] = t; s += t; s2 += t * t;
    }
#pragma unroll
    for (int o = 32; o > 0; o >>= 1) {
        s += __shfl_down(s, o);
        s2 += __shfl_down(s2, o);
    }
    __shared__ float ws1[4], ws2[4];
    int lane = tid & 63, w = tid >> 6;
    if (lane == 0) { ws1[w] = s; ws2[w] = s2; }
    __syncthreads();
    __shared__ float mu_s, rs_s;
    if (tid == 0) {
        float a = 0.f, b = 0.f;
        for (int i = 0; i < 4; i++) { a += ws1[i]; b += ws2[i]; }
        float mu = a / (float)HH;
        float var = b / (float)HH - mu * mu;
        mu_s = mu;
        rs_s = rsqrtf(var + 1e-12f);
    }
    __syncthreads();
    float mu = mu_s, rs = rs_s;
#pragma unroll
    for (int j = 0; j < 3; j++) {
        int h = tid + j * 256;
        float o = (v[j] - mu) * rs * gamma[h] + beta[h];
        out[(size_t)tok * HH + h] = o;
    }
}

// ================= fallback (small ws) kernels =================
__global__ __launch_bounds__(256) void gemm1_s(const float* __restrict__ X,
                                               const float* __restrict__ W1,
                                               const float* __restrict__ B1,
                                               const int* __restrict__ tok_sorted,
                                               const int* __restrict__ off,
                                               ushort* __restrict__ inter) {
    int slot = blockIdx.x;
    int e = slot >> 7, tile = slot & 127;
    int start = off[e] + (tile << 6);
    int end = off[e + 1];
    if (start >= end) return;
    int rows = end - start; if (rows > 64) rows = 64;
    int n0 = blockIdx.y << 6;
    const float* W1e = W1 + (size_t)e * HH * II;
    __shared__ ushort As[64 * 32];
    __shared__ ushort Bt[64 * 32];
    int tid = threadIdx.x;
    int w = tid >> 6, lane = tid & 63, m = lane & 15, quad = lane >> 4;
    int rrA = tid >> 2, c8A = tid & 3;
    int tokA = tok_sorted[start + (rrA < rows ? rrA : 0)];
    const float* gA = X + (size_t)tokA * HH + c8A * 8;
    int kB = tid >> 3, n8 = tid & 7;
    const float* gB = W1e + (size_t)kB * II + n0 + n8 * 8;
    f32x4 acc[4] = {};
    for (int k0 = 0; k0 < HH; k0 += 32) {
        float4 a0 = *(const float4*)(gA + k0);
        float4 a1 = *(const float4*)(gA + k0 + 4);
        float4 b0 = *(const float4*)(gB + (size_t)k0 * II);
        float4 b1 = *(const float4*)(gB + (size_t)k0 * II + 4);
        __syncthreads();
        union { ushort u[8]; uint4 v; } ta;
        ta.u[0] = f2b(a0.x); ta.u[1] = f2b(a0.y); ta.u[2] = f2b(a0.z); ta.u[3] = f2b(a0.w);
        ta.u[4] = f2b(a1.x); ta.u[5] = f2b(a1.y); ta.u[6] = f2b(a1.z); ta.u[7] = f2b(a1.w);
        *(uint4*)&As[rrA * 32 + c8A * 8] = ta.v;
        float bb[8] = {b0.x, b0.y, b0.z, b0.w, b1.x, b1.y, b1.z, b1.w};
#pragma unroll
        for (int j = 0; j < 8; j++) Bt[(n8 * 8 + j) * 32 + kB] = f2b(bb[j]);
        __syncthreads();
        bf16x8 a = *(const bf16x8*)&As[(w * 16 + m) * 32 + quad * 8];
#pragma unroll
        for (int nb = 0; nb < 4; nb++) {
            bf16x8 b = *(const bf16x8*)&Bt[(nb * 16 + m) * 32 + quad * 8];
            acc[nb] = __builtin_amdgcn_mfma_f32_16x16x32_bf16(a, b, acc[nb], 0, 0, 0);
        }
    }
    const float* b1e = B1 + (size_t)e * II;
#pragma unroll
    for (int nb = 0; nb < 4; nb++) {
        int col = n0 + nb * 16 + m;
        float bias = b1e[col];
#pragma unroll
        for (int r = 0; r < 4; r++) {
            int row = w * 16 + quad * 4 + r;
            if (row < rows) {
                float v = acc[nb][r] + bias;
                inter[(size_t)(start + row) * II + col] = f2b(fast_gelu(v));
            }
        }
    }
}

__global__ __launch_bounds__(256) void gemm2_s(const ushort* __restrict__ inter,
                                               const float* __restrict__ W2,
                                               const float* __restrict__ B2,
                                               const int* __restrict__ off,
                                               float* __restrict__ sel) {
    int slot = blockIdx.x;
    int e = slot >> 7, tile = slot & 127;
    int start = off[e] + (tile << 6);
    int end = off[e + 1];
    if (start >= end) return;
    int rows = end - start; if (rows > 64) rows = 64;
    int n0 = blockIdx.y << 6;
    const float* W2e = W2 + (size_t)e * II * HH;
    __shared__ ushort As[64 * 32];
    __shared__ ushort Bt[64 * 32];
    int tid = threadIdx.x;
    int w = tid >> 6, lane = tid & 63, m = lane & 15, quad = lane >> 4;
    int rrA = tid >> 2, c8A = tid & 3;
    int rA = start + rrA; if (rA > TT - 1) rA = TT - 1;
    const ushort* gA = inter + (size_t)rA * II + c8A * 8;
    int kB = tid >> 3, n8 = tid & 7;
    const float* gB = W2e + (size_t)kB * HH + n0 + n8 * 8;
    f32x4 acc[4] = {};
    for (int k0 = 0; k0 < II; k0 += 32) {
        uint4 av = *(const uint4*)(gA + k0);
        float4 b0 = *(const float4*)(gB + (size_t)k0 * HH);
        float4 b1 = *(const float4*)(gB + (size_t)k0 * HH + 4);
        __syncthreads();
        *(uint4*)&As[rrA * 32 + c8A * 8] = av;
        float bb[8] = {b0.x, b0.y, b0.z, b0.w, b1.x, b1.y, b1.z, b1.w};
#pragma unroll
        for (int j = 0; j < 8; j++) Bt[(n8 * 8 + j) * 32 + kB] = f2b(bb[j]);
        __syncthreads();
        bf16x8 a = *(const bf16x8*)&As[(w * 16 + m) * 32 + quad * 8];
#pragma unroll
        for (int nb = 0; nb < 4; nb++) {
            bf16x8 b = *(const bf16x8*)&Bt[(nb * 16 + m) * 32 + quad * 8];
            acc[nb] = __builtin_amdgcn_mfma_f32_16x16x32_bf16(a, b, acc[nb], 0, 0, 0);
        }
    }
    const float* b2e = B2 + (size_t)e * HH;
#pragma unroll
    for (int nb = 0; nb < 4; nb++) {
        int col = n0 + nb * 16 + m;
        float bias = b2e[col];
#pragma unroll
        for (int r = 0; r < 4; r++) {
            int row = w * 16 + quad * 4 + r;
            if (row < rows) sel[(size_t)(start + row) * HH + col] = acc[nb][r] + bias;
        }
    }
}

extern "C" void kernel_launch(void* const* d_in, const int* in_sizes, int n_in,
                              void* d_out, int out_size, void* d_ws, size_t ws_size,
                              hipStream_t stream) {
    const float* X  = (const float*)d_in[0];
    const float* W1 = (const float*)d_in[1];
    const float* B1 = (const float*)d_in[2];
    const float* W2 = (const float*)d_in[3];
    const float* B2 = (const float*)d_in[4];
    const float* G  = (const float*)d_in[5];
    const float* Bt = (const float*)d_in[6];
    const int* eids = (const int*)d_in[7];
    float* out = (float*)d_out;
    char* ws = (char*)d_ws;

    const size_t XS_OFF    = 34816;
    const size_t XS_SZ     = (size_t)2 * (TT + 128) * HH;
    const size_t W1T_OFF   = XS_OFF + XS_SZ;
    const size_t W1T_SZ    = (size_t)2 * EE * HH * II;
    const size_t W2T_OFF   = W1T_OFF + W1T_SZ;
    const size_t INTER_OFF = W2T_OFF + W1T_SZ;
    const size_t INTER_SZ  = (size_t)2 * (TT + 128) * II;
    const size_t SEL_OFF   = INTER_OFF + INTER_SZ;
    const size_t SEL_SZ    = (size_t)4 * TT * HH;
    const size_t NEED      = SEL_OFF + SEL_SZ;

    if (ws_size >= NEED) {
        int* off = (int*)ws;
        int* meta = (int*)(ws + 64);
        int* tok = (int*)(ws + 2048);
        ushort* Xs = (ushort*)(ws + XS_OFF);
        ushort* W1t = (ushort*)(ws + W1T_OFF);
        ushort* W2t = (ushort*)(ws + W2T_OFF);
        ushort* inter = (ushort*)(ws + INTER_OFF);
        float* sel = (float*)(ws + SEL_OFF);

        build_perm<<<1, 1024, 0, stream>>>(eids, tok, off, meta, 1);
        cvtX<<<TT, 192, 0, stream>>>(X, tok, Xs);
        tcvt2<<<dim3(576, EE, 2), 256, 0, stream>>>(W1, W2, W1t, W2t);
        gemm_k<HH, II, true, false, false><<<dim3(MAXT, II / 128), 256, 0, stream>>>(Xs, W1t, B1, nullptr, meta, inter);
        gemm_k<II, HH, false, true, true><<<dim3(MAXT, HH / 128), 256, 0, stream>>>(inter, W2t, B2, Xs, meta, sel);
        ln_kernel<<<TT, 256, 0, stream>>>(sel, X, G, Bt, tok, out, 0);
    } else {
        int* off = (int*)ws;
        int* tok = (int*)(ws + 64);
        ushort* inter = (ushort*)(ws + 64 + 4 * TT);
        float* sel = (float*)(ws + 64 + 4 * TT + (size_t)2 * TT * II);
        build_perm<<<1, 1024, 0, stream>>>(eids, tok, off, off, 0);
        gemm1_s<<<dim3(EE * 128, II / 64), 256, 0, stream>>>(X, W1, B1, tok, off, inter);
        gemm2_s<<<dim3(EE * 128, HH / 64), 256, 0, stream>>>(inter, W2, B2, off, sel);
        ln_kernel<<<TT, 256, 0, stream>>>(sel, X, G, Bt, tok, out, 1);
    }
}